// Round 6
// baseline (202.812 us; speedup 1.0000x reference)
//
#include <hip/hip_runtime.h>
#include <math.h>

#define CK __restrict__

constexpr int CH = 256;
constexpr int HW = 1024;   // 32*32

typedef __attribute__((ext_vector_type(8))) short short8;
typedef __attribute__((ext_vector_type(4))) float f32x4;

__device__ __forceinline__ ushort f2b(float x) {   // fp32 -> bf16 RNE
    union { float f; unsigned int u; } a; a.f = x;
    unsigned int r = (a.u + 0x7FFFu + ((a.u >> 16) & 1u)) >> 16;
    return (ushort)r;
}
__device__ __forceinline__ short8 ld8(const ushort* p) { return *(const short8*)p; }
__device__ __forceinline__ float u2f(unsigned int u) {
    union { unsigned int u; float f; } a; a.u = u; return a.f;
}
__device__ __forceinline__ float b2f(ushort us) { return u2f((unsigned int)us << 16); }

// ---------------------------------------------------------------------------
// prep: blocks 0..255  : four 256x256 weights -> bf16
//       blocks 256..383: x fp32 [b][c][n] -> xT bf16 [b][n][c]
//       blocks 384..391: pack rpe head table as padded bf16 x-pairs,
//                        pitch 67 (odd mod 32 -> LDS-conflict-friendly)
// ---------------------------------------------------------------------------
__global__ __launch_bounds__(256) void prep(const float* CK w0, const float* CK w1,
                                            const float* CK w2, const float* CK w3,
                                            ushort* CK o0, ushort* CK o1,
                                            ushort* CK o2, ushort* CK o3,
                                            const float* CK x, ushort* CK xT,
                                            const float* CK rpe, unsigned int* CK rpetab) {
    const int bid = blockIdx.x, t = threadIdx.x;
    if (bid < 256) {
        const float* src; ushort* dst;
        switch (bid >> 6) {
            case 0: src = w0; dst = o0; break;
            case 1: src = w1; dst = o1; break;
            case 2: src = w2; dst = o2; break;
            default: src = w3; dst = o3; break;
        }
        const int i = (bid & 63) * 256 + t;
        float4 v = ((const float4*)src)[i];
        ushort4 r; r.x = f2b(v.x); r.y = f2b(v.y); r.z = f2b(v.z); r.w = f2b(v.w);
        ((ushort4*)dst)[i] = r;
    } else if (bid < 384) {
        const int b2 = bid - 256;          // 0..127
        const int c8 = b2 & 31, b = b2 >> 5;
        for (int nn = 0; nn < 4; nn++) {
            const int n = nn * 256 + t;
            union { ushort u[8]; short8 s; } pk;
#pragma unroll
            for (int j = 0; j < 8; j++) pk.u[j] = f2b(x[(b * 256 + c8 * 8 + j) * HW + n]);
            *(short8*)(xT + b * 262144 + n * 256 + c8 * 8) = pk.s;
        }
    } else {
        const int h = bid - 384;           // head 0..7
        const float* rp = rpe + h * 3969;
        unsigned int* dst = rpetab + h * 4356;
        for (int i = t; i < 4356; i += 256) {
            int y = i / 67, x2 = i - y * 67;
            int yy = y - 1, xx = x2 - 1;
            bool vy = (yy >= 0) && (yy < 63) && (y < 65);
            float a  = (vy && xx >= 0 && xx < 63) ? rp[yy * 63 + xx] : 0.f;
            float bb = (vy && xx >= -1 && xx < 62) ? rp[yy * 63 + xx + 1] : 0.f;
            dst[i] = (unsigned int)f2b(a) | ((unsigned int)f2b(bb) << 16);
        }
    }
}

// ---------------------------------------------------------------------------
// MFMA GEMM, fp32 out: Y[b][m][n] = sum_c W[m][c] * A^T[n][c] + bias[m].
// Wave-tile 16m x 16n, grid (16 n64, 16 m16, 4 b) = 1024 blocks -> 16 waves/CU.
// ---------------------------------------------------------------------------
__global__ __launch_bounds__(256) void gemm_f32(const ushort* CK AT, const ushort* CK W,
                                                const float* CK bias, float* CK Y) {
    const int b = blockIdx.z;
    const int t = threadIdx.x, w = t >> 6, l = t & 63;
    const int lm = l & 15, qd = l >> 4;
    const int m0 = blockIdx.y * 16;
    const int np = blockIdx.x * 64 + w * 16;
    const ushort* A  = AT + b * 262144 + (np + lm) * 256;
    const ushort* Bm = W + (m0 + lm) * 256;
    f32x4 acc = {0.f, 0.f, 0.f, 0.f};
#pragma unroll
    for (int k0 = 0; k0 < 8; k0++) {
        const int ko = k0 * 32 + qd * 8;
        acc = __builtin_amdgcn_mfma_f32_16x16x32_bf16(ld8(A + ko), ld8(Bm + ko), acc, 0, 0, 0);
    }
    const float bs = bias[m0 + lm];
    float4 r;
    r.x = acc[0] + bs; r.y = acc[1] + bs; r.z = acc[2] + bs; r.w = acc[3] + bs;
    *(float4*)(Y + b * 262144 + (m0 + lm) * HW + np + qd * 4) = r;
}

// ---------------------------------------------------------------------------
// Fused K+V MFMA GEMM, bf16 fragment-linear outputs (same formats as r5).
// Wave-tile 16ch x 16pix, 2 accumulators; grid (16,16,4) = 1024 blocks.
// ---------------------------------------------------------------------------
__global__ __launch_bounds__(256) void gemm_kv(const ushort* CK AT,
                                               const ushort* CK Wk, const float* CK bk, ushort* CK kbt,
                                               const ushort* CK Wv, const float* CK bv, ushort* CK vbs) {
    const int b = blockIdx.z;
    const int t = threadIdx.x, w = t >> 6, l = t & 63;
    const int lm = l & 15, qd = l >> 4;
    const int m0 = blockIdx.y * 16;
    const int np = blockIdx.x * 64 + w * 16;
    const ushort* A  = AT + b * 262144 + (np + lm) * 256;
    const ushort* Kw = Wk + (m0 + lm) * 256;
    const ushort* Vw = Wv + (m0 + lm) * 256;
    f32x4 akT = {0.f, 0.f, 0.f, 0.f}, av = {0.f, 0.f, 0.f, 0.f};
#pragma unroll
    for (int k0 = 0; k0 < 8; k0++) {
        const int ko = k0 * 32 + qd * 8;
        short8 a = ld8(A + ko);
        akT = __builtin_amdgcn_mfma_f32_16x16x32_bf16(ld8(Kw + ko), a, akT, 0, 0, 0);
        av  = __builtin_amdgcn_mfma_f32_16x16x32_bf16(a, ld8(Vw + ko), av, 0, 0, 0);
    }
    {   // K: lane holds K[ch0+r][pix], ch0 = m0+qd*4, pix = np+lm
        const int ch0 = m0 + qd * 4;
        const int pix = np + lm;
        const int bh = b * 8 + (ch0 >> 5);
        const int qdk = (ch0 & 31) >> 3, co4 = ch0 & 7;
        const int nc = pix >> 7, nbk = (pix >> 4) & 7, lmk = pix & 15;
        const float4 bks = *(const float4*)(bk + ch0);
        ushort4 r4;
        r4.x = f2b(akT[0] + bks.x); r4.y = f2b(akT[1] + bks.y);
        r4.z = f2b(akT[2] + bks.z); r4.w = f2b(akT[3] + bks.w);
        *(ushort4*)(kbt + ((bh * 8 + nc) * 512 + nbk * 64 + qdk * 16 + lmk) * 8 + co4) = r4;
    }
    {   // V: lane holds V[ch][pix0+r], ch = m0+lm, pix0 = np+qd*4
        const int ch = m0 + lm;
        const int pix0 = np + qd * 4;
        const int bh = b * 8 + (ch >> 5);
        const int cb = (ch & 31) >> 4, lmv = ch & 15;
        const int nc = pix0 >> 7, kc = (pix0 >> 5) & 3;
        const int qdv = (pix0 >> 3) & 3, co0 = pix0 & 7;
        const float bs = bv[ch];
        ushort4 r4;
        r4.x = f2b(av[0] + bs); r4.y = f2b(av[1] + bs);
        r4.z = f2b(av[2] + bs); r4.w = f2b(av[3] + bs);
        *(ushort4*)(vbs + ((bh * 8 + nc) * 512 + (cb * 4 + kc) * 64 + qdv * 16 + lmv) * 8 + co0) = r4;
    }
}

// ---------------------------------------------------------------------------
// Depthwise 5x5 conv, pad 2.
// ---------------------------------------------------------------------------
__global__ __launch_bounds__(256) void dwconv(const float* CK q, const float* CK wdw,
                                              const float* CK bdw, float* CK off) {
    const int bx = blockIdx.x;
    const int ch = bx & 63;
    const float* qb = q + bx * HW;
    float w[25];
#pragma unroll
    for (int i = 0; i < 25; i++) w[i] = wdw[ch * 25 + i];
    const float bb = bdw[ch];
    const int t = threadIdx.x;
#pragma unroll
    for (int p = 0; p < 4; p++) {
        int hw = p * 256 + t;
        int ii = hw >> 5, jj = hw & 31;
        float s = bb;
#pragma unroll
        for (int ky = 0; ky < 5; ky++) {
            int y = ii + ky - 2;
            if (y < 0 || y > 31) continue;
#pragma unroll
            for (int kx = 0; kx < 5; kx++) {
                int x = jj + kx - 2;
                if (x < 0 || x > 31) continue;
                s += qb[y * 32 + x] * w[ky * 5 + kx];
            }
        }
        off[bx * HW + hw] = s;
    }
}

// ---------------------------------------------------------------------------
// LN(64)+GELU+proj+tanh -> pos (+outputs 1,2, scaled pos) + bilinear sample.
// 4 threads per pixel (qtr = t&3 owns 16 channels); shfl-combined reductions.
// grid 256 x 256 -> 4 waves/CU.
// ---------------------------------------------------------------------------
__global__ __launch_bounds__(256) void lnps(const float* CK off, const float* CK ln_g,
                                            const float* CK ln_b, const float* CK wpj,
                                            const float* CK x,
                                            float* CK out_pos, float* CK out_ref,
                                            float2* CK pos_sc, ushort* CK xsT) {
    const int bid = blockIdx.x, t = threadIdx.x;
    const int bg = bid >> 4;
    const int pix_l = t >> 2, qtr = t & 3;
    const int n = (bid & 15) * 64 + pix_l;
    const int gid = bg * 1024 + n;
    const float* ob = off + bg * 64 * HW + n;
    const int c0 = qtr * 16;
    float s1 = 0.f;
#pragma unroll
    for (int j = 0; j < 16; j++) s1 += ob[(c0 + j) * HW];
    s1 += __shfl_xor(s1, 1); s1 += __shfl_xor(s1, 2);
    const float mean = s1 * 0.015625f;
    float s2 = 0.f;
#pragma unroll
    for (int j = 0; j < 16; j++) { float d = ob[(c0 + j) * HW] - mean; s2 += d * d; }
    s2 += __shfl_xor(s2, 1); s2 += __shfl_xor(s2, 2);
    const float rs = rsqrtf(s2 * 0.015625f + 1e-5f);
    float p0 = 0.f, p1 = 0.f;
#pragma unroll
    for (int j = 0; j < 16; j++) {
        float vv = (ob[(c0 + j) * HW] - mean) * rs * ln_g[c0 + j] + ln_b[c0 + j];
        float gl = 0.5f * vv * (1.f + erff(vv * 0.70710678118654752f));
        p0 += gl * wpj[c0 + j];
        p1 += gl * wpj[64 + c0 + j];
    }
    p0 += __shfl_xor(p0, 1); p0 += __shfl_xor(p0, 2);
    p1 += __shfl_xor(p1, 1); p1 += __shfl_xor(p1, 2);
    const int ii = n >> 5, jj = n & 31;
    const float r0 = (jj + 0.5f) * 0.0625f - 1.f;   // ref ch0 <- column (meshgrid-xy)
    const float r1 = (ii + 0.5f) * 0.0625f - 1.f;   // ref ch1 <- row
    const float pos0 = tanhf(p0) * 0.0625f + r0;
    const float pos1 = tanhf(p1) * 0.0625f + r1;
    if (qtr == 0) {
        out_pos[gid * 2] = pos0; out_pos[gid * 2 + 1] = pos1;
        out_ref[gid * 2] = r0;   out_ref[gid * 2 + 1] = r1;
        pos_sc[gid].x = pos0 * 15.5f; pos_sc[gid].y = pos1 * 15.5f;
    }
    // bilinear sample (gx <- pos1, gy <- pos0), each lane does its 16 channels
    const float gx = (pos1 + 1.f) * 15.5f, gy = (pos0 + 1.f) * 15.5f;
    const float x0f = floorf(gx), y0f = floorf(gy);
    const float wx1 = gx - x0f, wx0 = 1.f - wx1, wy1 = gy - y0f, wy0 = 1.f - wy1;
    const bool vx0 = (x0f >= 0.f) && (x0f <= 31.f);
    const bool vx1 = (x0f >= -1.f) && (x0f <= 30.f);
    const bool vy0 = (y0f >= 0.f) && (y0f <= 31.f);
    const bool vy1 = (y0f >= -1.f) && (y0f <= 30.f);
    const int xi0 = (int)fminf(fmaxf(x0f, 0.f), 31.f);
    const int xi1 = (int)fminf(fmaxf(x0f + 1.f, 0.f), 31.f);
    const int yi0 = (int)fminf(fmaxf(y0f, 0.f), 31.f);
    const int yi1 = (int)fminf(fmaxf(y0f + 1.f, 0.f), 31.f);
    const float w00 = (vy0 && vx0) ? wy0 * wx0 : 0.f;
    const float w01 = (vy0 && vx1) ? wy0 * wx1 : 0.f;
    const float w10 = (vy1 && vx0) ? wy1 * wx0 : 0.f;
    const float w11 = (vy1 && vx1) ? wy1 * wx1 : 0.f;
    const int o00 = yi0 * 32 + xi0, o01 = yi0 * 32 + xi1;
    const int o10 = yi1 * 32 + xi0, o11 = yi1 * 32 + xi1;
    const int b = bg >> 2, g = bg & 3;
    const float* xb = x + bg * 64 * HW;
    ushort* xo = xsT + b * 262144 + n * 256 + g * 64 + c0;
#pragma unroll
    for (int j4 = 0; j4 < 4; j4++) {
        ushort4 r4;
        float vals[4];
#pragma unroll
        for (int j = 0; j < 4; j++) {
            const float* p = xb + (c0 + j4 * 4 + j) * HW;
            vals[j] = w00 * p[o00] + w01 * p[o01] + w10 * p[o10] + w11 * p[o11];
        }
        r4.x = f2b(vals[0]); r4.y = f2b(vals[1]); r4.z = f2b(vals[2]); r4.w = f2b(vals[3]);
        *(ushort4*)(xo + j4 * 4) = r4;
    }
}

// ---------------------------------------------------------------------------
// MFMA flash attention, barrier-free chunk loop, n-split x2.
// grid (16 m-tiles, 32 bh, 2 half) = 1024 blocks -> 4 blocks/CU, 4 waves/SIMD.
// K/V/pos read directly from global (fragment-linear, coalesced, L2-served).
// LDS: rpe pair table (pitch 67) + wave-private P only (~34.8 KB).
// Partials: unnormalized O (bf16) + (rmax, rsum) per m-row -> combine kernel.
// ---------------------------------------------------------------------------
__global__ __launch_bounds__(256, 4) void attn_part(const float* CK q, const ushort* CK kbt,
                                                    const ushort* CK vbs, const float2* CK pos_sc,
                                                    const unsigned int* CK rpetab,
                                                    ushort* CK partO, float2* CK mlbuf) {
    __shared__ __align__(16) unsigned int rpe_pr[4356];      // 65 x pitch-67 pairs
    __shared__ __align__(16) ushort Pl[4][2176];             // per-wave 8 blk x 272
    const int bh = blockIdx.y, half = blockIdx.z;
    const int b = bh >> 3, nh = bh & 7, bg = bh >> 1;
    const int t = threadIdx.x;
    const int w = t >> 6, l = t & 63;
    const int lm = l & 15, qd = l >> 4;

    {   // bulk-load packed rpe table (built in prep)
        const uint4* src4 = (const uint4*)(rpetab + nh * 4356);
        uint4* dst4 = (uint4*)rpe_pr;
        for (int i = t; i < 1089; i += 256) dst4[i] = src4[i];
    }
    __syncthreads();          // the only block-wide barrier

    const int m = blockIdx.x * 64 + w * 16 + lm;
    short8 qf;
    {
        union { ushort u[8]; short8 s; } pk;
        const float* qb = q + (b * 256 + nh * 32) * HW + m;
#pragma unroll
        for (int j = 0; j < 8; j++) pk.u[j] = f2b(qb[(qd * 8 + j) * HW]);
        qf = pk.s;
    }
    const float qg0 = ((m & 31) + 0.5f) * 0.0625f - 1.f;
    const float qg1 = ((m >> 5) + 0.5f) * 0.0625f - 1.f;
    const float ax = 31.f + 15.5f * qg1;   // gx = ax - sc_pos1
    const float ay = 31.f + 15.5f * qg0;   // gy = ay - sc_pos0

    f32x4 oacc0 = {0.f, 0.f, 0.f, 0.f}, oacc1 = {0.f, 0.f, 0.f, 0.f};
    float rmax = -3e38f, rsum = 0.f;
    ushort* PlW = Pl[w];
    const float2* pbase = pos_sc + bg * 1024;

    for (int nc = half * 4; nc < half * 4 + 4; nc++) {
        const ushort* kg = kbt + (bh * 8 + nc) * 4096;
        const ushort* vg = vbs + (bh * 8 + nc) * 4096;

        // QK^T: S^T[n][m], 8 MFMAs, K-frags straight from global
        f32x4 sT[8];
#pragma unroll
        for (int nb = 0; nb < 8; nb++) {
            sT[nb] = __builtin_amdgcn_mfma_f32_16x16x32_bf16(ld8(kg + (nb * 64 + l) * 8), qf,
                        (f32x4){0.f, 0.f, 0.f, 0.f}, 0, 0, 0);
        }

        // bias + scale
        float cmax = -3e38f;
#pragma unroll
        for (int nb = 0; nb < 8; nb++) {
            const float4* pp = (const float4*)(pbase + nc * 128 + nb * 16 + qd * 4);
            const float4 pa = pp[0], pb_ = pp[1];
            const float psx[4] = {pa.x, pa.z, pb_.x, pb_.z};
            const float psy[4] = {pa.y, pa.w, pb_.y, pb_.w};
#pragma unroll
            for (int r = 0; r < 4; r++) {
                const float gx = ax - psy[r];
                const float gy = ay - psx[r];
                const float x0f = floorf(gx), y0f = floorf(gy);
                const float wx1 = gx - x0f, wy1 = gy - y0f;
                const int idx = (int)y0f * 67 + (int)x0f + 68;
                const unsigned int pr0 = rpe_pr[idx];
                const unsigned int pr1 = rpe_pr[idx + 67];
                const float t00 = u2f(pr0 << 16), t01 = u2f(pr0 & 0xFFFF0000u);
                const float t10 = u2f(pr1 << 16), t11 = u2f(pr1 & 0xFFFF0000u);
                const float u0 = t00 + wx1 * (t01 - t00);
                const float u1 = t10 + wx1 * (t11 - t10);
                const float bias = u0 + wy1 * (u1 - u0);
                sT[nb][r] = sT[nb][r] * 0.17677669529663687f + bias;
                cmax = fmaxf(cmax, sT[nb][r]);
            }
        }
        cmax = fmaxf(cmax, __shfl_xor(cmax, 16));
        cmax = fmaxf(cmax, __shfl_xor(cmax, 32));
        const float newmax = fmaxf(rmax, cmax);
        const float alpha = __expf(rmax - newmax);
        rmax = newmax;

        // P = exp(s - max) -> bf16 wave-private LDS (D-linear, conflict-free)
        float csum = 0.f;
#pragma unroll
        for (int nb = 0; nb < 8; nb++) {
            float e0 = __expf(sT[nb][0] - rmax);
            float e1 = __expf(sT[nb][1] - rmax);
            float e2 = __expf(sT[nb][2] - rmax);
            float e3 = __expf(sT[nb][3] - rmax);
            csum += (e0 + e1) + (e2 + e3);
            uint2 pk;
            pk.x = (unsigned int)f2b(e0) | ((unsigned int)f2b(e1) << 16);
            pk.y = (unsigned int)f2b(e2) | ((unsigned int)f2b(e3) << 16);
            *(uint2*)(PlW + nb * 272 + l * 4) = pk;
        }
        csum += __shfl_xor(csum, 16);
        csum += __shfl_xor(csum, 32);
        rsum = rsum * alpha + csum;
        oacc0 *= alpha;
        oacc1 *= alpha;

        // PV: O^T[c][m] += V[c][n] * P^T[n][m], V-frags from global
#pragma unroll
        for (int kc = 0; kc < 4; kc++) {
            const ushort* pb2 = PlW + (kc * 2 + (qd >> 1)) * 272 + (qd & 1) * 128 + lm * 4;
            union { uint2 u[2]; short8 s; } pfu;
            pfu.u[0] = *(const uint2*)pb2;
            pfu.u[1] = *(const uint2*)(pb2 + 64);
            oacc0 = __builtin_amdgcn_mfma_f32_16x16x32_bf16(ld8(vg + (kc * 64 + l) * 8), pfu.s, oacc0, 0, 0, 0);
            oacc1 = __builtin_amdgcn_mfma_f32_16x16x32_bf16(ld8(vg + ((4 + kc) * 64 + l) * 8), pfu.s, oacc1, 0, 0, 0);
        }
    }

    // partial epilogue: unnormalized O (bf16) + (rmax, rsum)
    ushort* po = partO + (((half * 32 + bh) * 1024 + m) * 32) + qd * 4;
    ushort4 r04, r14;
    r04.x = f2b(oacc0[0]); r04.y = f2b(oacc0[1]); r04.z = f2b(oacc0[2]); r04.w = f2b(oacc0[3]);
    r14.x = f2b(oacc1[0]); r14.y = f2b(oacc1[1]); r14.z = f2b(oacc1[2]); r14.w = f2b(oacc1[3]);
    *(ushort4*)po = r04;
    *(ushort4*)(po + 16) = r14;
    if (qd == 0) {
        float2 ml; ml.x = rmax; ml.y = rsum;
        mlbuf[(half * 32 + bh) * 1024 + m] = ml;
    }
}

// ---------------------------------------------------------------------------
// Combine the two n-halves: O = (O0*e0 + O1*e1) / (l0*e0 + l1*e1), -> aoT bf16.
// grid 128 x 256; thread owns one (bh, m) row of 32 channels.
// ---------------------------------------------------------------------------
__global__ __launch_bounds__(256) void attn_comb(const ushort* CK partO, const float2* CK mlbuf,
                                                 ushort* CK aoT) {
    const int gid = blockIdx.x * 256 + threadIdx.x;   // 0..32767
    const int bh = gid >> 10, m = gid & 1023;
    const int b = bh >> 3, nh = bh & 7;
    const float2 ml0 = mlbuf[bh * 1024 + m];
    const float2 ml1 = mlbuf[(32 + bh) * 1024 + m];
    const float M = fmaxf(ml0.x, ml1.x);
    const float e0 = __expf(ml0.x - M), e1 = __expf(ml1.x - M);
    const float inv = 1.f / (ml0.y * e0 + ml1.y * e1);
    const float w0 = e0 * inv, w1 = e1 * inv;
    const ushort* p0 = partO + (bh * 1024 + m) * 32;
    const ushort* p1 = partO + ((32 + bh) * 1024 + m) * 32;
    ushort* ob = aoT + b * 262144 + m * 256 + nh * 32;
#pragma unroll
    for (int h = 0; h < 2; h++) {
        union { ushort u[8]; short8 s; } a, c, o;
        a.s = ld8(p0 + h * 8 + (h >> 1) * 0);  // contiguous halves below
        a.s = ld8(p0 + h * 16);
        c.s = ld8(p1 + h * 16);
        // wait: each short8 covers 8 channels; need 2 pairs per h -> do 8+8
#pragma unroll
        for (int j = 0; j < 8; j++) o.u[j] = f2b(b2f(a.u[j]) * w0 + b2f(c.u[j]) * w1);
        *(short8*)(ob + h * 16) = o.s;
        union { ushort u[8]; short8 s; } a2, c2, o2;
        a2.s = ld8(p0 + h * 16 + 8);
        c2.s = ld8(p1 + h * 16 + 8);
#pragma unroll
        for (int j = 0; j < 8; j++) o2.u[j] = f2b(b2f(a2.u[j]) * w0 + b2f(c2.u[j]) * w1);
        *(short8*)(ob + h * 16 + 8) = o2.s;
    }
}

// ---------------------------------------------------------------------------
extern "C" void kernel_launch(void* const* d_in, const int* in_sizes, int n_in,
                              void* d_out, int out_size, void* d_ws, size_t ws_size,
                              hipStream_t stream) {
    (void)in_sizes; (void)n_in; (void)out_size; (void)ws_size;
    const float* x   = (const float*)d_in[0];
    const float* wq  = (const float*)d_in[1];
    const float* bq  = (const float*)d_in[2];
    const float* wdw = (const float*)d_in[3];
    const float* bdw = (const float*)d_in[4];
    const float* lng = (const float*)d_in[5];
    const float* lnb = (const float*)d_in[6];
    const float* wpj = (const float*)d_in[7];
    const float* wk  = (const float*)d_in[8];
    const float* bk  = (const float*)d_in[9];
    const float* wv  = (const float*)d_in[10];
    const float* bv  = (const float*)d_in[11];
    const float* wo  = (const float*)d_in[12];
    const float* bo  = (const float*)d_in[13];
    const float* rpe = (const float*)d_in[14];
    float* outp = (float*)d_out;
    char* base = (char*)d_ws;
    const size_t MB = 1 << 20;

    float*  q_ws   = (float*)(base);                        // 4 MB
    float*  off_ws = (float*)(base + 4 * MB);               // 4 MB (-> partO)
    ushort* partO  = (ushort*)(base + 4 * MB);              // 4 MB, after lnps
    float2* pos_sc = (float2*)(base + 8 * MB);              // 128 KB
    ushort* xT     = (ushort*)(base + 8 * MB + 131072);     // 2 MB (-> mlbuf)
    float2* mlbuf  = (float2*)(base + 8 * MB + 131072);     // 512 KB, after q-gemm
    ushort* xsT    = (ushort*)(base + 10 * MB + 131072);    // 2 MB
    ushort* kbt    = (ushort*)(base + 12 * MB + 131072);    // 2 MB
    ushort* vbs    = (ushort*)(base + 14 * MB + 131072);    // 2 MB
    ushort* aoT    = (ushort*)(base + 16 * MB + 131072);    // 2 MB
    ushort* wqb    = (ushort*)(base + 18 * MB + 131072);
    ushort* wkb    = (ushort*)(base + 18 * MB + 262144);
    ushort* wvb    = (ushort*)(base + 18 * MB + 393216);
    ushort* wob    = (ushort*)(base + 18 * MB + 524288);
    unsigned int* rpetab = (unsigned int*)(base + 18 * MB + 655360);  // 139 KB

    prep<<<392, 256, 0, stream>>>(wq, wk, wv, wo, wqb, wkb, wvb, wob, x, xT, rpe, rpetab);
    gemm_f32<<<dim3(16, 16, 4), 256, 0, stream>>>(xT, wqb, bq, q_ws);
    dwconv<<<1024, 256, 0, stream>>>(q_ws, wdw, bdw, off_ws);
    lnps<<<256, 256, 0, stream>>>(off_ws, lng, lnb, wpj, x,
                                  outp + (1 << 20), outp + (1 << 20) + 32768, pos_sc, xsT);
    gemm_kv<<<dim3(16, 16, 4), 256, 0, stream>>>(xsT, wkb, bk, kbt, wvb, bv, vbs);
    attn_part<<<dim3(16, 32, 2), 256, 0, stream>>>(q_ws, kbt, vbs, pos_sc, rpetab, partO, mlbuf);
    attn_comb<<<128, 256, 0, stream>>>(partO, mlbuf, aoT);
    gemm_f32<<<dim3(16, 16, 4), 256, 0, stream>>>(aoT, wob, bo, outp);
}

// Round 7
// 188.778 us; speedup vs baseline: 1.0743x; 1.0743x over previous
//
#include <hip/hip_runtime.h>
#include <math.h>

#define CK __restrict__

constexpr int CH = 256;
constexpr int HW = 1024;   // 32*32

typedef __attribute__((ext_vector_type(8))) short short8;
typedef __attribute__((ext_vector_type(4))) float f32x4;

__device__ __forceinline__ ushort f2b(float x) {   // fp32 -> bf16 RNE
    union { float f; unsigned int u; } a; a.f = x;
    unsigned int r = (a.u + 0x7FFFu + ((a.u >> 16) & 1u)) >> 16;
    return (ushort)r;
}
__device__ __forceinline__ short8 ld8(const ushort* p) { return *(const short8*)p; }
__device__ __forceinline__ float u2f(unsigned int u) {
    union { unsigned int u; float f; } a; a.u = u; return a.f;
}
__device__ __forceinline__ float b2f(ushort us) { return u2f((unsigned int)us << 16); }

// ---------------------------------------------------------------------------
// prep: blocks 0..255  : four 256x256 weights -> bf16
//       blocks 256..383: x fp32 [b][c][n] -> xT bf16 [b][n][c]
//       blocks 384..391: rpe head -> padded bf16 x-pair table, pitch 67
// ---------------------------------------------------------------------------
__global__ __launch_bounds__(256) void prep(const float* CK w0, const float* CK w1,
                                            const float* CK w2, const float* CK w3,
                                            ushort* CK o0, ushort* CK o1,
                                            ushort* CK o2, ushort* CK o3,
                                            const float* CK x, ushort* CK xT,
                                            const float* CK rpe, unsigned int* CK rpetab) {
    const int bid = blockIdx.x, t = threadIdx.x;
    if (bid < 256) {
        const float* src; ushort* dst;
        switch (bid >> 6) {
            case 0: src = w0; dst = o0; break;
            case 1: src = w1; dst = o1; break;
            case 2: src = w2; dst = o2; break;
            default: src = w3; dst = o3; break;
        }
        const int i = (bid & 63) * 256 + t;
        float4 v = ((const float4*)src)[i];
        ushort4 r; r.x = f2b(v.x); r.y = f2b(v.y); r.z = f2b(v.z); r.w = f2b(v.w);
        ((ushort4*)dst)[i] = r;
    } else if (bid < 384) {
        const int b2 = bid - 256;          // 0..127
        const int c8 = b2 & 31, b = b2 >> 5;
        for (int nn = 0; nn < 4; nn++) {
            const int n = nn * 256 + t;
            union { ushort u[8]; short8 s; } pk;
#pragma unroll
            for (int j = 0; j < 8; j++) pk.u[j] = f2b(x[(b * 256 + c8 * 8 + j) * HW + n]);
            *(short8*)(xT + b * 262144 + n * 256 + c8 * 8) = pk.s;
        }
    } else {
        const int h = bid - 384;           // head 0..7
        const float* rp = rpe + h * 3969;
        unsigned int* dst = rpetab + h * 4356;
        for (int i = t; i < 4356; i += 256) {
            int y = i / 67, x2 = i - y * 67;
            int yy = y - 1, xx = x2 - 1;
            bool vy = (yy >= 0) && (yy < 63) && (y < 65);
            float a  = (vy && xx >= 0 && xx < 63) ? rp[yy * 63 + xx] : 0.f;
            float bb = (vy && xx >= -1 && xx < 62) ? rp[yy * 63 + xx + 1] : 0.f;
            dst[i] = (unsigned int)f2b(a) | ((unsigned int)f2b(bb) << 16);
        }
    }
}

// ---------------------------------------------------------------------------
// MFMA GEMM (r5-style: 64x64 block, 4 waves of 32x32, 2x2 indep acc chains),
// bf16 out: Q = W*xT + bias.  grid (16 nt, 4 mt, 4 b).
// ---------------------------------------------------------------------------
__global__ __launch_bounds__(256) void gemm_q(const ushort* CK AT, const ushort* CK W,
                                              const float* CK bias, ushort* CK Y) {
    const int b = blockIdx.z;
    const int t = threadIdx.x, w = t >> 6, l = t & 63;
    const int lm = l & 15, qd = l >> 4;
    const int m0 = blockIdx.y * 64 + (w & 1) * 32;
    const int n0 = blockIdx.x * 64 + (w >> 1) * 32;
    const ushort* A = AT + b * 262144 + n0 * 256;
    const ushort* Bm = W + m0 * 256;
    f32x4 acc[2][2] = {};
#pragma unroll
    for (int k0 = 0; k0 < 8; k0++) {
        const int ko = k0 * 32 + qd * 8;
        short8 a0 = ld8(A + lm * 256 + ko);
        short8 a1 = ld8(A + (16 + lm) * 256 + ko);
        short8 b0 = ld8(Bm + lm * 256 + ko);
        short8 b1 = ld8(Bm + (16 + lm) * 256 + ko);
        acc[0][0] = __builtin_amdgcn_mfma_f32_16x16x32_bf16(a0, b0, acc[0][0], 0, 0, 0);
        acc[0][1] = __builtin_amdgcn_mfma_f32_16x16x32_bf16(a0, b1, acc[0][1], 0, 0, 0);
        acc[1][0] = __builtin_amdgcn_mfma_f32_16x16x32_bf16(a1, b0, acc[1][0], 0, 0, 0);
        acc[1][1] = __builtin_amdgcn_mfma_f32_16x16x32_bf16(a1, b1, acc[1][1], 0, 0, 0);
    }
#pragma unroll
    for (int in = 0; in < 2; in++)
#pragma unroll
        for (int im = 0; im < 2; im++) {
            const int m = m0 + im * 16 + lm;
            const float bs = bias[m];
            ushort4 r;
            r.x = f2b(acc[in][im][0] + bs); r.y = f2b(acc[in][im][1] + bs);
            r.z = f2b(acc[in][im][2] + bs); r.w = f2b(acc[in][im][3] + bs);
            *(ushort4*)(Y + b * 262144 + m * HW + n0 + in * 16 + qd * 4) = r;
        }
}

// ---------------------------------------------------------------------------
// Same structure, fp32 out (final projection).
// ---------------------------------------------------------------------------
__global__ __launch_bounds__(256) void gemm_o(const ushort* CK AT, const ushort* CK W,
                                              const float* CK bias, float* CK Y) {
    const int b = blockIdx.z;
    const int t = threadIdx.x, w = t >> 6, l = t & 63;
    const int lm = l & 15, qd = l >> 4;
    const int m0 = blockIdx.y * 64 + (w & 1) * 32;
    const int n0 = blockIdx.x * 64 + (w >> 1) * 32;
    const ushort* A = AT + b * 262144 + n0 * 256;
    const ushort* Bm = W + m0 * 256;
    f32x4 acc[2][2] = {};
#pragma unroll
    for (int k0 = 0; k0 < 8; k0++) {
        const int ko = k0 * 32 + qd * 8;
        short8 a0 = ld8(A + lm * 256 + ko);
        short8 a1 = ld8(A + (16 + lm) * 256 + ko);
        short8 b0 = ld8(Bm + lm * 256 + ko);
        short8 b1 = ld8(Bm + (16 + lm) * 256 + ko);
        acc[0][0] = __builtin_amdgcn_mfma_f32_16x16x32_bf16(a0, b0, acc[0][0], 0, 0, 0);
        acc[0][1] = __builtin_amdgcn_mfma_f32_16x16x32_bf16(a0, b1, acc[0][1], 0, 0, 0);
        acc[1][0] = __builtin_amdgcn_mfma_f32_16x16x32_bf16(a1, b0, acc[1][0], 0, 0, 0);
        acc[1][1] = __builtin_amdgcn_mfma_f32_16x16x32_bf16(a1, b1, acc[1][1], 0, 0, 0);
    }
#pragma unroll
    for (int in = 0; in < 2; in++)
#pragma unroll
        for (int im = 0; im < 2; im++) {
            const int m = m0 + im * 16 + lm;
            const float bs = bias[m];
            float4 r;
            r.x = acc[in][im][0] + bs; r.y = acc[in][im][1] + bs;
            r.z = acc[in][im][2] + bs; r.w = acc[in][im][3] + bs;
            *(float4*)(Y + b * 262144 + m * HW + n0 + in * 16 + qd * 4) = r;
        }
}

// ---------------------------------------------------------------------------
// Fused K+V MFMA GEMM (r5-style blocks), bf16 fragment-linear outputs.
// K uses swapped operands -> 4 consecutive channels per lane -> ushort4.
// ---------------------------------------------------------------------------
__global__ __launch_bounds__(256) void gemm_kv(const ushort* CK AT,
                                               const ushort* CK Wk, const float* CK bk, ushort* CK kbt,
                                               const ushort* CK Wv, const float* CK bv, ushort* CK vbs) {
    const int b = blockIdx.z;
    const int t = threadIdx.x, w = t >> 6, l = t & 63;
    const int lm = l & 15, qd = l >> 4;
    const int m0 = blockIdx.y * 64 + (w & 1) * 32;
    const int n0 = blockIdx.x * 64 + (w >> 1) * 32;
    const ushort* A = AT + b * 262144 + n0 * 256;
    const ushort* Bk = Wk + m0 * 256;
    const ushort* Bv = Wv + m0 * 256;
    f32x4 akT[2][2] = {}, av[2][2] = {};
#pragma unroll
    for (int k0 = 0; k0 < 8; k0++) {
        const int ko = k0 * 32 + qd * 8;
        short8 a0 = ld8(A + lm * 256 + ko);
        short8 a1 = ld8(A + (16 + lm) * 256 + ko);
        short8 k0f = ld8(Bk + lm * 256 + ko);
        short8 k1f = ld8(Bk + (16 + lm) * 256 + ko);
        short8 v0f = ld8(Bv + lm * 256 + ko);
        short8 v1f = ld8(Bv + (16 + lm) * 256 + ko);
        akT[0][0] = __builtin_amdgcn_mfma_f32_16x16x32_bf16(k0f, a0, akT[0][0], 0, 0, 0);
        akT[0][1] = __builtin_amdgcn_mfma_f32_16x16x32_bf16(k0f, a1, akT[0][1], 0, 0, 0);
        akT[1][0] = __builtin_amdgcn_mfma_f32_16x16x32_bf16(k1f, a0, akT[1][0], 0, 0, 0);
        akT[1][1] = __builtin_amdgcn_mfma_f32_16x16x32_bf16(k1f, a1, akT[1][1], 0, 0, 0);
        av[0][0] = __builtin_amdgcn_mfma_f32_16x16x32_bf16(a0, v0f, av[0][0], 0, 0, 0);
        av[0][1] = __builtin_amdgcn_mfma_f32_16x16x32_bf16(a0, v1f, av[0][1], 0, 0, 0);
        av[1][0] = __builtin_amdgcn_mfma_f32_16x16x32_bf16(a1, v0f, av[1][0], 0, 0, 0);
        av[1][1] = __builtin_amdgcn_mfma_f32_16x16x32_bf16(a1, v1f, av[1][1], 0, 0, 0);
    }
#pragma unroll
    for (int im = 0; im < 2; im++)
#pragma unroll
        for (int in = 0; in < 2; in++) {
            {   // K: lane holds K[c0+r][n], c0 = m0+im*16+qd*4, n = n0+in*16+lm
                const int c0 = m0 + im * 16 + qd * 4;
                const int n  = n0 + in * 16 + lm;
                const int bh = b * 8 + (c0 >> 5);
                const int qdk = (c0 & 31) >> 3, co4 = c0 & 7;
                const int nc = n >> 7, nbk = (n >> 4) & 7, lmk = n & 15;
                const float4 bks = *(const float4*)(bk + c0);
                ushort4 r4;
                r4.x = f2b(akT[im][in][0] + bks.x);
                r4.y = f2b(akT[im][in][1] + bks.y);
                r4.z = f2b(akT[im][in][2] + bks.z);
                r4.w = f2b(akT[im][in][3] + bks.w);
                *(ushort4*)(kbt + ((bh * 8 + nc) * 512 + nbk * 64 + qdk * 16 + lmk) * 8 + co4) = r4;
            }
            {   // V: lane holds V[c][nbase+r], c = m0+im*16+lm
                const int c = m0 + im * 16 + lm;
                const int bh = b * 8 + (c >> 5);
                const float bs = bv[c];
                const int cb = (c & 31) >> 4, lmv = c & 15;
                const int nbase = n0 + in * 16 + qd * 4;
                const int nc = nbase >> 7, kc = (nbase >> 5) & 3;
                const int qdv = (nbase >> 3) & 3, co0 = nbase & 7;
                ushort4 r4;
                r4.x = f2b(av[in][im][0] + bs); r4.y = f2b(av[in][im][1] + bs);
                r4.z = f2b(av[in][im][2] + bs); r4.w = f2b(av[in][im][3] + bs);
                *(ushort4*)(vbs + ((bh * 8 + nc) * 512 + (cb * 4 + kc) * 64 + qdv * 16 + lmv) * 8 + co0) = r4;
            }
        }
}

// ---------------------------------------------------------------------------
// Depthwise 5x5 conv, pad 2 — q is now bf16.
// ---------------------------------------------------------------------------
__global__ __launch_bounds__(256) void dwconv(const ushort* CK q, const float* CK wdw,
                                              const float* CK bdw, float* CK off) {
    const int bx = blockIdx.x;
    const int ch = bx & 63;
    const ushort* qb = q + bx * HW;
    float w[25];
#pragma unroll
    for (int i = 0; i < 25; i++) w[i] = wdw[ch * 25 + i];
    const float bb = bdw[ch];
    const int t = threadIdx.x;
#pragma unroll
    for (int p = 0; p < 4; p++) {
        int hw = p * 256 + t;
        int ii = hw >> 5, jj = hw & 31;
        float s = bb;
#pragma unroll
        for (int ky = 0; ky < 5; ky++) {
            int y = ii + ky - 2;
            if (y < 0 || y > 31) continue;
#pragma unroll
            for (int kx = 0; kx < 5; kx++) {
                int x = jj + kx - 2;
                if (x < 0 || x > 31) continue;
                s += b2f(qb[y * 32 + x]) * w[ky * 5 + kx];
            }
        }
        off[bx * HW + hw] = s;
    }
}

// ---------------------------------------------------------------------------
// LN(64)+GELU+proj+tanh -> pos (+outputs 1,2, scaled pos) + bilinear sample.
// 4 threads/pixel; channel values hoisted into registers (single load pass).
// ---------------------------------------------------------------------------
__global__ __launch_bounds__(256) void lnps(const float* CK off, const float* CK ln_g,
                                            const float* CK ln_b, const float* CK wpj,
                                            const float* CK x,
                                            float* CK out_pos, float* CK out_ref,
                                            float2* CK pos_sc, ushort* CK xsT) {
    const int bid = blockIdx.x, t = threadIdx.x;
    const int bg = bid >> 4;
    const int pix_l = t >> 2, qtr = t & 3;
    const int n = (bid & 15) * 64 + pix_l;
    const int gid = bg * 1024 + n;
    const float* ob = off + bg * 64 * HW + n;
    const int c0 = qtr * 16;
    float v[16];
    float s1 = 0.f;
#pragma unroll
    for (int j = 0; j < 16; j++) { v[j] = ob[(c0 + j) * HW]; s1 += v[j]; }
    s1 += __shfl_xor(s1, 1); s1 += __shfl_xor(s1, 2);
    const float mean = s1 * 0.015625f;
    float s2 = 0.f;
#pragma unroll
    for (int j = 0; j < 16; j++) { float d = v[j] - mean; s2 += d * d; }
    s2 += __shfl_xor(s2, 1); s2 += __shfl_xor(s2, 2);
    const float rs = rsqrtf(s2 * 0.015625f + 1e-5f);
    float p0 = 0.f, p1 = 0.f;
#pragma unroll
    for (int j = 0; j < 16; j++) {
        float vv = (v[j] - mean) * rs * ln_g[c0 + j] + ln_b[c0 + j];
        float gl = 0.5f * vv * (1.f + erff(vv * 0.70710678118654752f));
        p0 += gl * wpj[c0 + j];
        p1 += gl * wpj[64 + c0 + j];
    }
    p0 += __shfl_xor(p0, 1); p0 += __shfl_xor(p0, 2);
    p1 += __shfl_xor(p1, 1); p1 += __shfl_xor(p1, 2);
    const int ii = n >> 5, jj = n & 31;
    const float r0 = (jj + 0.5f) * 0.0625f - 1.f;   // ref ch0 <- column (meshgrid-xy)
    const float r1 = (ii + 0.5f) * 0.0625f - 1.f;   // ref ch1 <- row
    const float pos0 = tanhf(p0) * 0.0625f + r0;
    const float pos1 = tanhf(p1) * 0.0625f + r1;
    if (qtr == 0) {
        out_pos[gid * 2] = pos0; out_pos[gid * 2 + 1] = pos1;
        out_ref[gid * 2] = r0;   out_ref[gid * 2 + 1] = r1;
        pos_sc[gid].x = pos0 * 15.5f; pos_sc[gid].y = pos1 * 15.5f;
    }
    const float gx = (pos1 + 1.f) * 15.5f, gy = (pos0 + 1.f) * 15.5f;
    const float x0f = floorf(gx), y0f = floorf(gy);
    const float wx1 = gx - x0f, wx0 = 1.f - wx1, wy1 = gy - y0f, wy0 = 1.f - wy1;
    const bool vx0 = (x0f >= 0.f) && (x0f <= 31.f);
    const bool vx1 = (x0f >= -1.f) && (x0f <= 30.f);
    const bool vy0 = (y0f >= 0.f) && (y0f <= 31.f);
    const bool vy1 = (y0f >= -1.f) && (y0f <= 30.f);
    const int xi0 = (int)fminf(fmaxf(x0f, 0.f), 31.f);
    const int xi1 = (int)fminf(fmaxf(x0f + 1.f, 0.f), 31.f);
    const int yi0 = (int)fminf(fmaxf(y0f, 0.f), 31.f);
    const int yi1 = (int)fminf(fmaxf(y0f + 1.f, 0.f), 31.f);
    const float w00 = (vy0 && vx0) ? wy0 * wx0 : 0.f;
    const float w01 = (vy0 && vx1) ? wy0 * wx1 : 0.f;
    const float w10 = (vy1 && vx0) ? wy1 * wx0 : 0.f;
    const float w11 = (vy1 && vx1) ? wy1 * wx1 : 0.f;
    const int o00 = yi0 * 32 + xi0, o01 = yi0 * 32 + xi1;
    const int o10 = yi1 * 32 + xi0, o11 = yi1 * 32 + xi1;
    const int b = bg >> 2, g = bg & 3;
    const float* xb = x + bg * 64 * HW;
    ushort* xo = xsT + b * 262144 + n * 256 + g * 64 + c0;
#pragma unroll
    for (int j4 = 0; j4 < 4; j4++) {
        ushort4 r4;
        float vals[4];
#pragma unroll
        for (int j = 0; j < 4; j++) {
            const float* p = xb + (c0 + j4 * 4 + j) * HW;
            vals[j] = w00 * p[o00] + w01 * p[o01] + w10 * p[o10] + w11 * p[o11];
        }
        r4.x = f2b(vals[0]); r4.y = f2b(vals[1]); r4.z = f2b(vals[2]); r4.w = f2b(vals[3]);
        *(ushort4*)(xo + j4 * 4) = r4;
    }
}

// ---------------------------------------------------------------------------
// MFMA flash attention, n-split x4, 32-n-granular pipeline (tiny P buffer).
// grid (16 mt, 32 bh, 4 quarter) = 2048 blocks; LDS = rpe 17.4K + Pl 4.25K
// = 21.8 KB -> 7 blocks/CU = 28 waves/CU.  One barrier (rpe load).
// ---------------------------------------------------------------------------
__global__ __launch_bounds__(256, 7) void attn_part(const ushort* CK q, const ushort* CK kbt,
                                                    const ushort* CK vbs, const float2* CK pos_sc,
                                                    const unsigned int* CK rpetab,
                                                    ushort* CK partO, float2* CK mlbuf) {
    __shared__ __align__(16) unsigned int rpe_pr[4356];      // 65 x pitch-67 pairs
    __shared__ __align__(16) ushort Pl[4][544];              // per-wave 2 blk x 272
    const int bh = blockIdx.y, quarter = blockIdx.z;
    const int b = bh >> 3, nh = bh & 7, bg = bh >> 1;
    const int t = threadIdx.x;
    const int w = t >> 6, l = t & 63;
    const int lm = l & 15, qd = l >> 4;

    {   // bulk-load packed rpe table (built in prep)
        const uint4* src4 = (const uint4*)(rpetab + nh * 4356);
        uint4* dst4 = (uint4*)rpe_pr;
        for (int i = t; i < 1089; i += 256) dst4[i] = src4[i];
    }
    __syncthreads();

    const int m = blockIdx.x * 64 + w * 16 + lm;
    short8 qf;
    {
        union { ushort u[8]; short8 s; } pk;
        const ushort* qb = q + (b * 256 + nh * 32) * HW + m;
#pragma unroll
        for (int j = 0; j < 8; j++) pk.u[j] = qb[(qd * 8 + j) * HW];
        qf = pk.s;
    }
    const float qg0 = ((m & 31) + 0.5f) * 0.0625f - 1.f;
    const float qg1 = ((m >> 5) + 0.5f) * 0.0625f - 1.f;
    const float ax = 31.f + 15.5f * qg1;   // gx = ax - sc_pos1
    const float ay = 31.f + 15.5f * qg0;   // gy = ay - sc_pos0

    f32x4 oacc0 = {0.f, 0.f, 0.f, 0.f}, oacc1 = {0.f, 0.f, 0.f, 0.f};
    float rmax = -3e38f, rsum = 0.f;
    ushort* PlW = Pl[w];
    const float2* pbase = pos_sc + bg * 1024;

    for (int nc = quarter * 2; nc < quarter * 2 + 2; nc++) {
        const ushort* kg = kbt + (bh * 8 + nc) * 4096;
        const ushort* vg = vbs + (bh * 8 + nc) * 4096;

#pragma unroll
        for (int nb2 = 0; nb2 < 4; nb2++) {           // 32-n groups
            // QK^T for 32 n: 2 MFMAs
            f32x4 sT[2];
#pragma unroll
            for (int s = 0; s < 2; s++) {
                const int nb = nb2 * 2 + s;
                sT[s] = __builtin_amdgcn_mfma_f32_16x16x32_bf16(
                            ld8(kg + (nb * 64 + l) * 8), qf,
                            (f32x4){0.f, 0.f, 0.f, 0.f}, 0, 0, 0);
            }
            // bias + scale for the 8 owned cells
            float cmax = -3e38f;
#pragma unroll
            for (int s = 0; s < 2; s++) {
                const float4* pp = (const float4*)(pbase + nc * 128 + (nb2 * 2 + s) * 16 + qd * 4);
                const float4 pa = pp[0], pb_ = pp[1];
                const float psx[4] = {pa.x, pa.z, pb_.x, pb_.z};
                const float psy[4] = {pa.y, pa.w, pb_.y, pb_.w};
#pragma unroll
                for (int r = 0; r < 4; r++) {
                    const float gx = ax - psy[r];
                    const float gy = ay - psx[r];
                    const float x0f = floorf(gx), y0f = floorf(gy);
                    const float wx1 = gx - x0f, wy1 = gy - y0f;
                    const int idx = (int)y0f * 67 + (int)x0f + 68;
                    const unsigned int pr0 = rpe_pr[idx];
                    const unsigned int pr1 = rpe_pr[idx + 67];
                    const float t00 = u2f(pr0 << 16), t01 = u2f(pr0 & 0xFFFF0000u);
                    const float t10 = u2f(pr1 << 16), t11 = u2f(pr1 & 0xFFFF0000u);
                    const float u0 = t00 + wx1 * (t01 - t00);
                    const float u1 = t10 + wx1 * (t11 - t10);
                    sT[s][r] = sT[s][r] * 0.17677669529663687f + (u0 + wy1 * (u1 - u0));
                    cmax = fmaxf(cmax, sT[s][r]);
                }
            }
            cmax = fmaxf(cmax, __shfl_xor(cmax, 16));
            cmax = fmaxf(cmax, __shfl_xor(cmax, 32));
            const float newmax = fmaxf(rmax, cmax);
            const float alpha = __expf(rmax - newmax);
            rmax = newmax;
            // P = exp(s-max) -> wave-private LDS (2 slots)
            float csum = 0.f;
#pragma unroll
            for (int s = 0; s < 2; s++) {
                float e0 = __expf(sT[s][0] - rmax);
                float e1 = __expf(sT[s][1] - rmax);
                float e2 = __expf(sT[s][2] - rmax);
                float e3 = __expf(sT[s][3] - rmax);
                csum += (e0 + e1) + (e2 + e3);
                uint2 pk;
                pk.x = (unsigned int)f2b(e0) | ((unsigned int)f2b(e1) << 16);
                pk.y = (unsigned int)f2b(e2) | ((unsigned int)f2b(e3) << 16);
                *(uint2*)(PlW + s * 272 + l * 4) = pk;
            }
            csum += __shfl_xor(csum, 16);
            csum += __shfl_xor(csum, 32);
            rsum = rsum * alpha + csum;
            oacc0 *= alpha;
            oacc1 *= alpha;
            // PV for this 32-n group: one k-step, 2 MFMAs
            const ushort* pb2 = PlW + (qd >> 1) * 272 + (qd & 1) * 128 + lm * 4;
            union { uint2 u[2]; short8 s; } pfu;
            pfu.u[0] = *(const uint2*)pb2;
            pfu.u[1] = *(const uint2*)(pb2 + 64);
            oacc0 = __builtin_amdgcn_mfma_f32_16x16x32_bf16(ld8(vg + (nb2 * 64 + l) * 8), pfu.s, oacc0, 0, 0, 0);
            oacc1 = __builtin_amdgcn_mfma_f32_16x16x32_bf16(ld8(vg + ((4 + nb2) * 64 + l) * 8), pfu.s, oacc1, 0, 0, 0);
        }
    }

    // partial epilogue: unnormalized O (bf16) + (rmax, rsum)
    ushort* po = partO + (((quarter * 32 + bh) * 1024 + m) * 32) + qd * 4;
    ushort4 r04, r14;
    r04.x = f2b(oacc0[0]); r04.y = f2b(oacc0[1]); r04.z = f2b(oacc0[2]); r04.w = f2b(oacc0[3]);
    r14.x = f2b(oacc1[0]); r14.y = f2b(oacc1[1]); r14.z = f2b(oacc1[2]); r14.w = f2b(oacc1[3]);
    *(ushort4*)po = r04;
    *(ushort4*)(po + 16) = r14;
    if (qd == 0) {
        float2 ml; ml.x = rmax; ml.y = rsum;
        mlbuf[(quarter * 32 + bh) * 1024 + m] = ml;
    }
}

// ---------------------------------------------------------------------------
// 4-way combine: O = sum_i O_i*e_i / sum_i l_i*e_i -> aoT bf16 [b][n][c].
// ---------------------------------------------------------------------------
__global__ __launch_bounds__(128) void attn_comb(const ushort* CK partO, const float2* CK mlbuf,
                                                 ushort* CK aoT) {
    const int gid = blockIdx.x * 128 + threadIdx.x;   // 0..32767
    const int bh = gid >> 10, m = gid & 1023;
    const int b = bh >> 3, nh = bh & 7;
    float2 ml[4];
    float M = -3e38f;
#pragma unroll
    for (int i = 0; i < 4; i++) { ml[i] = mlbuf[(i * 32 + bh) * 1024 + m]; M = fmaxf(M, ml[i].x); }
    float e[4], denom = 0.f;
#pragma unroll
    for (int i = 0; i < 4; i++) { e[i] = __expf(ml[i].x - M); denom += ml[i].y * e[i]; }
    const float inv = 1.f / denom;
#pragma unroll
    for (int i = 0; i < 4; i++) e[i] *= inv;
    ushort* ob = aoT + b * 262144 + m * 256 + nh * 32;
#pragma unroll
    for (int g8 = 0; g8 < 4; g8++) {
        float acc[8] = {};
#pragma unroll
        for (int i = 0; i < 4; i++) {
            union { ushort u[8]; short8 s; } pv;
            pv.s = ld8(partO + ((i * 32 + bh) * 1024 + m) * 32 + g8 * 8);
#pragma unroll
            for (int j = 0; j < 8; j++) acc[j] += b2f(pv.u[j]) * e[i];
        }
        union { ushort u[8]; short8 s; } o;
#pragma unroll
        for (int j = 0; j < 8; j++) o.u[j] = f2b(acc[j]);
        *(short8*)(ob + g8 * 8) = o.s;
    }
}

// ---------------------------------------------------------------------------
extern "C" void kernel_launch(void* const* d_in, const int* in_sizes, int n_in,
                              void* d_out, int out_size, void* d_ws, size_t ws_size,
                              hipStream_t stream) {
    (void)in_sizes; (void)n_in; (void)out_size; (void)ws_size;
    const float* x   = (const float*)d_in[0];
    const float* wq  = (const float*)d_in[1];
    const float* bq  = (const float*)d_in[2];
    const float* wdw = (const float*)d_in[3];
    const float* bdw = (const float*)d_in[4];
    const float* lng = (const float*)d_in[5];
    const float* lnb = (const float*)d_in[6];
    const float* wpj = (const float*)d_in[7];
    const float* wk  = (const float*)d_in[8];
    const float* bk  = (const float*)d_in[9];
    const float* wv  = (const float*)d_in[10];
    const float* bv  = (const float*)d_in[11];
    const float* wo  = (const float*)d_in[12];
    const float* bo  = (const float*)d_in[13];
    const float* rpe = (const float*)d_in[14];
    float* outp = (float*)d_out;
    char* base = (char*)d_ws;
    const size_t MB = 1 << 20;

    ushort* q_b    = (ushort*)(base);                       // 2 MB  bf16 q
    ushort* kbt    = (ushort*)(base + 2 * MB);              // 2 MB
    ushort* vbs    = (ushort*)(base + 4 * MB);              // 2 MB
    // overlay region @6MB..14MB: {off 4MB @6, xT 2MB @10, xsT 2MB @12} then partO 8MB
    float*  off_ws = (float*)(base + 6 * MB);
    ushort* xT     = (ushort*)(base + 10 * MB);
    ushort* xsT    = (ushort*)(base + 12 * MB);
    ushort* partO  = (ushort*)(base + 6 * MB);
    float2* mlbuf  = (float2*)(base + 14 * MB);             // 1 MB
    ushort* aoT    = (ushort*)(base + 15 * MB);             // 2 MB
    ushort* wqb    = (ushort*)(base + 17 * MB);
    ushort* wkb    = (ushort*)(base + 17 * MB + 131072);
    ushort* wvb    = (ushort*)(base + 17 * MB + 262144);
    ushort* wob    = (ushort*)(base + 17 * MB + 393216);
    float2* pos_sc = (float2*)(base + 17 * MB + 524288);    // 128 KB
    unsigned int* rpetab = (unsigned int*)(base + 17 * MB + 655360);  // 139 KB

    prep<<<392, 256, 0, stream>>>(wq, wk, wv, wo, wqb, wkb, wvb, wob, x, xT, rpe, rpetab);
    gemm_q<<<dim3(16, 4, 4), 256, 0, stream>>>(xT, wqb, bq, q_b);
    dwconv<<<1024, 256, 0, stream>>>(q_b, wdw, bdw, off_ws);
    lnps<<<256, 256, 0, stream>>>(off_ws, lng, lnb, wpj, x,
                                  outp + (1 << 20), outp + (1 << 20) + 32768, pos_sc, xsT);
    gemm_kv<<<dim3(16, 4, 4), 256, 0, stream>>>(xsT, wkb, bk, kbt, wvb, bv, vbs);
    attn_part<<<dim3(16, 32, 4), 256, 0, stream>>>(q_b, kbt, vbs, pos_sc, rpetab, partO, mlbuf);
    attn_comb<<<256, 128, 0, stream>>>(partO, mlbuf, aoT);
    gemm_o<<<dim3(16, 4, 4), 256, 0, stream>>>(aoT, wob, bo, outp);
}

// Round 8
// 182.464 us; speedup vs baseline: 1.1115x; 1.0346x over previous
//
#include <hip/hip_runtime.h>
#include <math.h>

#define CK __restrict__

constexpr int CH = 256;
constexpr int HW = 1024;   // 32*32

typedef __attribute__((ext_vector_type(8))) short short8;
typedef __attribute__((ext_vector_type(4))) float f32x4;
typedef __attribute__((ext_vector_type(2))) float v2f;

__device__ __forceinline__ ushort f2b(float x) {   // fp32 -> bf16 RNE
    union { float f; unsigned int u; } a; a.f = x;
    unsigned int r = (a.u + 0x7FFFu + ((a.u >> 16) & 1u)) >> 16;
    return (ushort)r;
}
__device__ __forceinline__ short8 ld8(const ushort* p) { return *(const short8*)p; }
__device__ __forceinline__ float u2f(unsigned int u) {
    union { unsigned int u; float f; } a; a.u = u; return a.f;
}
__device__ __forceinline__ float b2f(ushort us) { return u2f((unsigned int)us << 16); }

// ---------------------------------------------------------------------------
// prep: blocks 0..255  : four 256x256 weights -> bf16
//       blocks 256..383: x fp32 [b][c][n] -> xT bf16 [b][n][c]
//       blocks 384..391: rpe head -> padded bf16 x-pair table, pitch 67
// ---------------------------------------------------------------------------
__global__ __launch_bounds__(256) void prep(const float* CK w0, const float* CK w1,
                                            const float* CK w2, const float* CK w3,
                                            ushort* CK o0, ushort* CK o1,
                                            ushort* CK o2, ushort* CK o3,
                                            const float* CK x, ushort* CK xT,
                                            const float* CK rpe, unsigned int* CK rpetab) {
    const int bid = blockIdx.x, t = threadIdx.x;
    if (bid < 256) {
        const float* src; ushort* dst;
        switch (bid >> 6) {
            case 0: src = w0; dst = o0; break;
            case 1: src = w1; dst = o1; break;
            case 2: src = w2; dst = o2; break;
            default: src = w3; dst = o3; break;
        }
        const int i = (bid & 63) * 256 + t;
        float4 v = ((const float4*)src)[i];
        ushort4 r; r.x = f2b(v.x); r.y = f2b(v.y); r.z = f2b(v.z); r.w = f2b(v.w);
        ((ushort4*)dst)[i] = r;
    } else if (bid < 384) {
        const int b2 = bid - 256;          // 0..127
        const int c8 = b2 & 31, b = b2 >> 5;
        for (int nn = 0; nn < 4; nn++) {
            const int n = nn * 256 + t;
            union { ushort u[8]; short8 s; } pk;
#pragma unroll
            for (int j = 0; j < 8; j++) pk.u[j] = f2b(x[(b * 256 + c8 * 8 + j) * HW + n]);
            *(short8*)(xT + b * 262144 + n * 256 + c8 * 8) = pk.s;
        }
    } else {
        const int h = bid - 384;           // head 0..7
        const float* rp = rpe + h * 3969;
        unsigned int* dst = rpetab + h * 4356;
        for (int i = t; i < 4356; i += 256) {
            int y = i / 67, x2 = i - y * 67;
            int yy = y - 1, xx = x2 - 1;
            bool vy = (yy >= 0) && (yy < 63) && (y < 65);
            float a  = (vy && xx >= 0 && xx < 63) ? rp[yy * 63 + xx] : 0.f;
            float bb = (vy && xx >= -1 && xx < 62) ? rp[yy * 63 + xx + 1] : 0.f;
            dst[i] = (unsigned int)f2b(a) | ((unsigned int)f2b(bb) << 16);
        }
    }
}

// ---------------------------------------------------------------------------
// MFMA GEMM (64x64 block, 4 waves of 32x32, 2x2 indep acc chains),
// bf16 out: Q = W*xT + bias.  grid (16 nt, 4 mt, 4 b).
// ---------------------------------------------------------------------------
__global__ __launch_bounds__(256) void gemm_q(const ushort* CK AT, const ushort* CK W,
                                              const float* CK bias, ushort* CK Y) {
    const int b = blockIdx.z;
    const int t = threadIdx.x, w = t >> 6, l = t & 63;
    const int lm = l & 15, qd = l >> 4;
    const int m0 = blockIdx.y * 64 + (w & 1) * 32;
    const int n0 = blockIdx.x * 64 + (w >> 1) * 32;
    const ushort* A = AT + b * 262144 + n0 * 256;
    const ushort* Bm = W + m0 * 256;
    f32x4 acc[2][2] = {};
#pragma unroll
    for (int k0 = 0; k0 < 8; k0++) {
        const int ko = k0 * 32 + qd * 8;
        short8 a0 = ld8(A + lm * 256 + ko);
        short8 a1 = ld8(A + (16 + lm) * 256 + ko);
        short8 b0 = ld8(Bm + lm * 256 + ko);
        short8 b1 = ld8(Bm + (16 + lm) * 256 + ko);
        acc[0][0] = __builtin_amdgcn_mfma_f32_16x16x32_bf16(a0, b0, acc[0][0], 0, 0, 0);
        acc[0][1] = __builtin_amdgcn_mfma_f32_16x16x32_bf16(a0, b1, acc[0][1], 0, 0, 0);
        acc[1][0] = __builtin_amdgcn_mfma_f32_16x16x32_bf16(a1, b0, acc[1][0], 0, 0, 0);
        acc[1][1] = __builtin_amdgcn_mfma_f32_16x16x32_bf16(a1, b1, acc[1][1], 0, 0, 0);
    }
#pragma unroll
    for (int in = 0; in < 2; in++)
#pragma unroll
        for (int im = 0; im < 2; im++) {
            const int m = m0 + im * 16 + lm;
            const float bs = bias[m];
            ushort4 r;
            r.x = f2b(acc[in][im][0] + bs); r.y = f2b(acc[in][im][1] + bs);
            r.z = f2b(acc[in][im][2] + bs); r.w = f2b(acc[in][im][3] + bs);
            *(ushort4*)(Y + b * 262144 + m * HW + n0 + in * 16 + qd * 4) = r;
        }
}

// ---------------------------------------------------------------------------
// Fused K+V MFMA GEMM, bf16 fragment-linear outputs.
// ---------------------------------------------------------------------------
__global__ __launch_bounds__(256) void gemm_kv(const ushort* CK AT,
                                               const ushort* CK Wk, const float* CK bk, ushort* CK kbt,
                                               const ushort* CK Wv, const float* CK bv, ushort* CK vbs) {
    const int b = blockIdx.z;
    const int t = threadIdx.x, w = t >> 6, l = t & 63;
    const int lm = l & 15, qd = l >> 4;
    const int m0 = blockIdx.y * 64 + (w & 1) * 32;
    const int n0 = blockIdx.x * 64 + (w >> 1) * 32;
    const ushort* A = AT + b * 262144 + n0 * 256;
    const ushort* Bk = Wk + m0 * 256;
    const ushort* Bv = Wv + m0 * 256;
    f32x4 akT[2][2] = {}, av[2][2] = {};
#pragma unroll
    for (int k0 = 0; k0 < 8; k0++) {
        const int ko = k0 * 32 + qd * 8;
        short8 a0 = ld8(A + lm * 256 + ko);
        short8 a1 = ld8(A + (16 + lm) * 256 + ko);
        short8 k0f = ld8(Bk + lm * 256 + ko);
        short8 k1f = ld8(Bk + (16 + lm) * 256 + ko);
        short8 v0f = ld8(Bv + lm * 256 + ko);
        short8 v1f = ld8(Bv + (16 + lm) * 256 + ko);
        akT[0][0] = __builtin_amdgcn_mfma_f32_16x16x32_bf16(k0f, a0, akT[0][0], 0, 0, 0);
        akT[0][1] = __builtin_amdgcn_mfma_f32_16x16x32_bf16(k0f, a1, akT[0][1], 0, 0, 0);
        akT[1][0] = __builtin_amdgcn_mfma_f32_16x16x32_bf16(k1f, a0, akT[1][0], 0, 0, 0);
        akT[1][1] = __builtin_amdgcn_mfma_f32_16x16x32_bf16(k1f, a1, akT[1][1], 0, 0, 0);
        av[0][0] = __builtin_amdgcn_mfma_f32_16x16x32_bf16(a0, v0f, av[0][0], 0, 0, 0);
        av[0][1] = __builtin_amdgcn_mfma_f32_16x16x32_bf16(a0, v1f, av[0][1], 0, 0, 0);
        av[1][0] = __builtin_amdgcn_mfma_f32_16x16x32_bf16(a1, v0f, av[1][0], 0, 0, 0);
        av[1][1] = __builtin_amdgcn_mfma_f32_16x16x32_bf16(a1, v1f, av[1][1], 0, 0, 0);
    }
#pragma unroll
    for (int im = 0; im < 2; im++)
#pragma unroll
        for (int in = 0; in < 2; in++) {
            {   // K: lane holds K[c0+r][n]
                const int c0 = m0 + im * 16 + qd * 4;
                const int n  = n0 + in * 16 + lm;
                const int bh = b * 8 + (c0 >> 5);
                const int qdk = (c0 & 31) >> 3, co4 = c0 & 7;
                const int nc = n >> 7, nbk = (n >> 4) & 7, lmk = n & 15;
                const float4 bks = *(const float4*)(bk + c0);
                ushort4 r4;
                r4.x = f2b(akT[im][in][0] + bks.x);
                r4.y = f2b(akT[im][in][1] + bks.y);
                r4.z = f2b(akT[im][in][2] + bks.z);
                r4.w = f2b(akT[im][in][3] + bks.w);
                *(ushort4*)(kbt + ((bh * 8 + nc) * 512 + nbk * 64 + qdk * 16 + lmk) * 8 + co4) = r4;
            }
            {   // V: lane holds V[c][nbase+r]
                const int c = m0 + im * 16 + lm;
                const int bh = b * 8 + (c >> 5);
                const float bs = bv[c];
                const int cb = (c & 31) >> 4, lmv = c & 15;
                const int nbase = n0 + in * 16 + qd * 4;
                const int nc = nbase >> 7, kc = (nbase >> 5) & 3;
                const int qdv = (nbase >> 3) & 3, co0 = nbase & 7;
                ushort4 r4;
                r4.x = f2b(av[in][im][0] + bs); r4.y = f2b(av[in][im][1] + bs);
                r4.z = f2b(av[in][im][2] + bs); r4.w = f2b(av[in][im][3] + bs);
                *(ushort4*)(vbs + ((bh * 8 + nc) * 512 + (cb * 4 + kc) * 64 + qdv * 16 + lmv) * 8 + co0) = r4;
            }
        }
}

// ---------------------------------------------------------------------------
// Depthwise 5x5 conv, pad 2 — q bf16.
// ---------------------------------------------------------------------------
__global__ __launch_bounds__(256) void dwconv(const ushort* CK q, const float* CK wdw,
                                              const float* CK bdw, float* CK off) {
    const int bx = blockIdx.x;
    const int ch = bx & 63;
    const ushort* qb = q + bx * HW;
    float w[25];
#pragma unroll
    for (int i = 0; i < 25; i++) w[i] = wdw[ch * 25 + i];
    const float bb = bdw[ch];
    const int t = threadIdx.x;
#pragma unroll
    for (int p = 0; p < 4; p++) {
        int hw = p * 256 + t;
        int ii = hw >> 5, jj = hw & 31;
        float s = bb;
#pragma unroll
        for (int ky = 0; ky < 5; ky++) {
            int y = ii + ky - 2;
            if (y < 0 || y > 31) continue;
#pragma unroll
            for (int kx = 0; kx < 5; kx++) {
                int x = jj + kx - 2;
                if (x < 0 || x > 31) continue;
                s += b2f(qb[y * 32 + x]) * w[ky * 5 + kx];
            }
        }
        off[bx * HW + hw] = s;
    }
}

// ---------------------------------------------------------------------------
// LN(64)+GELU+proj+tanh -> pos (+outputs 1,2, scaled pos) + bilinear sample.
// ---------------------------------------------------------------------------
__global__ __launch_bounds__(256) void lnps(const float* CK off, const float* CK ln_g,
                                            const float* CK ln_b, const float* CK wpj,
                                            const float* CK x,
                                            float* CK out_pos, float* CK out_ref,
                                            float2* CK pos_sc, ushort* CK xsT) {
    const int bid = blockIdx.x, t = threadIdx.x;
    const int bg = bid >> 4;
    const int pix_l = t >> 2, qtr = t & 3;
    const int n = (bid & 15) * 64 + pix_l;
    const int gid = bg * 1024 + n;
    const float* ob = off + bg * 64 * HW + n;
    const int c0 = qtr * 16;
    float v[16];
    float s1 = 0.f;
#pragma unroll
    for (int j = 0; j < 16; j++) { v[j] = ob[(c0 + j) * HW]; s1 += v[j]; }
    s1 += __shfl_xor(s1, 1); s1 += __shfl_xor(s1, 2);
    const float mean = s1 * 0.015625f;
    float s2 = 0.f;
#pragma unroll
    for (int j = 0; j < 16; j++) { float d = v[j] - mean; s2 += d * d; }
    s2 += __shfl_xor(s2, 1); s2 += __shfl_xor(s2, 2);
    const float rs = rsqrtf(s2 * 0.015625f + 1e-5f);
    float p0 = 0.f, p1 = 0.f;
#pragma unroll
    for (int j = 0; j < 16; j++) {
        float vv = (v[j] - mean) * rs * ln_g[c0 + j] + ln_b[c0 + j];
        float gl = 0.5f * vv * (1.f + erff(vv * 0.70710678118654752f));
        p0 += gl * wpj[c0 + j];
        p1 += gl * wpj[64 + c0 + j];
    }
    p0 += __shfl_xor(p0, 1); p0 += __shfl_xor(p0, 2);
    p1 += __shfl_xor(p1, 1); p1 += __shfl_xor(p1, 2);
    const int ii = n >> 5, jj = n & 31;
    const float r0 = (jj + 0.5f) * 0.0625f - 1.f;   // ref ch0 <- column (meshgrid-xy)
    const float r1 = (ii + 0.5f) * 0.0625f - 1.f;   // ref ch1 <- row
    const float pos0 = tanhf(p0) * 0.0625f + r0;
    const float pos1 = tanhf(p1) * 0.0625f + r1;
    if (qtr == 0) {
        out_pos[gid * 2] = pos0; out_pos[gid * 2 + 1] = pos1;
        out_ref[gid * 2] = r0;   out_ref[gid * 2 + 1] = r1;
        pos_sc[gid].x = pos0 * 15.5f; pos_sc[gid].y = pos1 * 15.5f;
    }
    const float gx = (pos1 + 1.f) * 15.5f, gy = (pos0 + 1.f) * 15.5f;
    const float x0f = floorf(gx), y0f = floorf(gy);
    const float wx1 = gx - x0f, wx0 = 1.f - wx1, wy1 = gy - y0f, wy0 = 1.f - wy1;
    const bool vx0 = (x0f >= 0.f) && (x0f <= 31.f);
    const bool vx1 = (x0f >= -1.f) && (x0f <= 30.f);
    const bool vy0 = (y0f >= 0.f) && (y0f <= 31.f);
    const bool vy1 = (y0f >= -1.f) && (y0f <= 30.f);
    const int xi0 = (int)fminf(fmaxf(x0f, 0.f), 31.f);
    const int xi1 = (int)fminf(fmaxf(x0f + 1.f, 0.f), 31.f);
    const int yi0 = (int)fminf(fmaxf(y0f, 0.f), 31.f);
    const int yi1 = (int)fminf(fmaxf(y0f + 1.f, 0.f), 31.f);
    const float w00 = (vy0 && vx0) ? wy0 * wx0 : 0.f;
    const float w01 = (vy0 && vx1) ? wy0 * wx1 : 0.f;
    const float w10 = (vy1 && vx0) ? wy1 * wx0 : 0.f;
    const float w11 = (vy1 && vx1) ? wy1 * wx1 : 0.f;
    const int o00 = yi0 * 32 + xi0, o01 = yi0 * 32 + xi1;
    const int o10 = yi1 * 32 + xi0, o11 = yi1 * 32 + xi1;
    const int b = bg >> 2, g = bg & 3;
    const float* xb = x + bg * 64 * HW;
    ushort* xo = xsT + b * 262144 + n * 256 + g * 64 + c0;
#pragma unroll
    for (int j4 = 0; j4 < 4; j4++) {
        ushort4 r4;
        float vals[4];
#pragma unroll
        for (int j = 0; j < 4; j++) {
            const float* p = xb + (c0 + j4 * 4 + j) * HW;
            vals[j] = w00 * p[o00] + w01 * p[o01] + w10 * p[o10] + w11 * p[o11];
        }
        r4.x = f2b(vals[0]); r4.y = f2b(vals[1]); r4.z = f2b(vals[2]); r4.w = f2b(vals[3]);
        *(ushort4*)(xo + j4 * 4) = r4;
    }
}

// ---------------------------------------------------------------------------
// MFMA flash attention, n-split x4, 64-n-granular (halved softmax chains).
// grid (16 mt, 32 bh, 4 quarter) = 2048 blocks; LDS = rpe 17.4K + Pl 8.7K.
// Bias: no floor (coords >= 0), packed v2f vertical lerp.
// ---------------------------------------------------------------------------
__global__ __launch_bounds__(256, 4) void attn_part(const ushort* CK q, const ushort* CK kbt,
                                                    const ushort* CK vbs, const float2* CK pos_sc,
                                                    const unsigned int* CK rpetab,
                                                    ushort* CK partO, float2* CK mlbuf) {
    __shared__ __align__(16) unsigned int rpe_pr[4356];      // 65 x pitch-67 bf16-pairs
    __shared__ __align__(16) ushort Pl[4][1088];             // per-wave 4 blk x 272
    const int bh = blockIdx.y, quarter = blockIdx.z;
    const int b = bh >> 3, nh = bh & 7, bg = bh >> 1;
    const int t = threadIdx.x;
    const int w = t >> 6, l = t & 63;
    const int lm = l & 15, qd = l >> 4;

    {   // bulk-load packed rpe table (built in prep)
        const uint4* src4 = (const uint4*)(rpetab + nh * 4356);
        uint4* dst4 = (uint4*)rpe_pr;
        for (int i = t; i < 1089; i += 256) dst4[i] = src4[i];
    }
    __syncthreads();

    const int m = blockIdx.x * 64 + w * 16 + lm;
    short8 qf;
    {
        union { ushort u[8]; short8 s; } pk;
        const ushort* qb = q + (b * 256 + nh * 32) * HW + m;
#pragma unroll
        for (int j = 0; j < 8; j++) pk.u[j] = qb[(qd * 8 + j) * HW];
        qf = pk.s;
    }
    const float qg0 = ((m & 31) + 0.5f) * 0.0625f - 1.f;
    const float qg1 = ((m >> 5) + 0.5f) * 0.0625f - 1.f;
    const float ax = 31.f + 15.5f * qg1;   // gx = ax - sc_pos1  (>= 0 always)
    const float ay = 31.f + 15.5f * qg0;   // gy = ay - sc_pos0  (>= 0 always)

    f32x4 oacc0 = {0.f, 0.f, 0.f, 0.f}, oacc1 = {0.f, 0.f, 0.f, 0.f};
    float rmax = -3e38f, rsum = 0.f;
    ushort* PlW = Pl[w];
    const float2* pbase = pos_sc + bg * 1024;

    for (int nc = quarter * 2; nc < quarter * 2 + 2; nc++) {
        const ushort* kg = kbt + (bh * 8 + nc) * 4096;
        const ushort* vg = vbs + (bh * 8 + nc) * 4096;

#pragma unroll
        for (int g = 0; g < 2; g++) {                 // 64-n groups
            // QK^T: 4 back-to-back MFMAs
            f32x4 sT[4];
#pragma unroll
            for (int s = 0; s < 4; s++) {
                const int nb = g * 4 + s;
                sT[s] = __builtin_amdgcn_mfma_f32_16x16x32_bf16(
                            ld8(kg + (nb * 64 + l) * 8), qf,
                            (f32x4){0.f, 0.f, 0.f, 0.f}, 0, 0, 0);
            }
            // bias + scale (16 owned cells)
            float cmax = -3e38f;
#pragma unroll
            for (int s = 0; s < 4; s++) {
                const float4* pp = (const float4*)(pbase + nc * 128 + (g * 4 + s) * 16 + qd * 4);
                const float4 pa = pp[0], pb_ = pp[1];
                const float psx[4] = {pa.x, pa.z, pb_.x, pb_.z};
                const float psy[4] = {pa.y, pa.w, pb_.y, pb_.w};
#pragma unroll
                for (int rp = 0; rp < 2; rp++) {
                    v2f gx = {ax - psy[rp * 2], ax - psy[rp * 2 + 1]};
                    v2f gy = {ay - psx[rp * 2], ay - psx[rp * 2 + 1]};
                    const int xi0 = (int)gx.x, xi1 = (int)gx.y;   // trunc == floor (>=0)
                    const int yi0 = (int)gy.x, yi1 = (int)gy.y;
                    v2f wx = gx - (v2f){(float)xi0, (float)xi1};
                    v2f wy = gy - (v2f){(float)yi0, (float)yi1};
                    const int idxA = yi0 * 67 + xi0 + 68;
                    const int idxB = yi1 * 67 + xi1 + 68;
                    const unsigned int a0 = rpe_pr[idxA], a1 = rpe_pr[idxA + 67];
                    const unsigned int b0 = rpe_pr[idxB], b1 = rpe_pr[idxB + 67];
                    v2f tA = {u2f(a0 << 16), u2f(a0 & 0xFFFF0000u)};
                    v2f bA = {u2f(a1 << 16), u2f(a1 & 0xFFFF0000u)};
                    v2f tB = {u2f(b0 << 16), u2f(b0 & 0xFFFF0000u)};
                    v2f bB = {u2f(b1 << 16), u2f(b1 & 0xFFFF0000u)};
                    v2f vA = tA + wy.x * (bA - tA);               // packed vertical lerp
                    v2f vB = tB + wy.y * (bB - tB);
                    const float biasA = vA.x + wx.x * (vA.y - vA.x);
                    const float biasB = vB.x + wx.y * (vB.y - vB.x);
                    sT[s][rp * 2]     = sT[s][rp * 2]     * 0.17677669529663687f + biasA;
                    sT[s][rp * 2 + 1] = sT[s][rp * 2 + 1] * 0.17677669529663687f + biasB;
                    cmax = fmaxf(cmax, fmaxf(sT[s][rp * 2], sT[s][rp * 2 + 1]));
                }
            }
            cmax = fmaxf(cmax, __shfl_xor(cmax, 16));
            cmax = fmaxf(cmax, __shfl_xor(cmax, 32));
            const float newmax = fmaxf(rmax, cmax);
            const float alpha = __expf(rmax - newmax);
            rmax = newmax;
            // P = exp(s-max) -> wave-private LDS (4 slots)
            float csum = 0.f;
#pragma unroll
            for (int s = 0; s < 4; s++) {
                float e0 = __expf(sT[s][0] - rmax);
                float e1 = __expf(sT[s][1] - rmax);
                float e2 = __expf(sT[s][2] - rmax);
                float e3 = __expf(sT[s][3] - rmax);
                csum += (e0 + e1) + (e2 + e3);
                uint2 pk;
                pk.x = (unsigned int)f2b(e0) | ((unsigned int)f2b(e1) << 16);
                pk.y = (unsigned int)f2b(e2) | ((unsigned int)f2b(e3) << 16);
                *(uint2*)(PlW + s * 272 + l * 4) = pk;
            }
            csum += __shfl_xor(csum, 16);
            csum += __shfl_xor(csum, 32);
            rsum = rsum * alpha + csum;
            oacc0 *= alpha;
            oacc1 *= alpha;
            // PV: 2 k-steps, 4 MFMAs
#pragma unroll
            for (int kc = 0; kc < 2; kc++) {
                const ushort* pb2 = PlW + (kc * 2 + (qd >> 1)) * 272 + (qd & 1) * 128 + lm * 4;
                union { uint2 u[2]; short8 s; } pfu;
                pfu.u[0] = *(const uint2*)pb2;
                pfu.u[1] = *(const uint2*)(pb2 + 64);
                const int kv = g * 2 + kc;
                oacc0 = __builtin_amdgcn_mfma_f32_16x16x32_bf16(ld8(vg + (kv * 64 + l) * 8), pfu.s, oacc0, 0, 0, 0);
                oacc1 = __builtin_amdgcn_mfma_f32_16x16x32_bf16(ld8(vg + ((4 + kv) * 64 + l) * 8), pfu.s, oacc1, 0, 0, 0);
            }
        }
    }

    // partial epilogue: unnormalized O (bf16) + (rmax, rsum)
    ushort* po = partO + (((quarter * 32 + bh) * 1024 + m) * 32) + qd * 4;
    ushort4 r04, r14;
    r04.x = f2b(oacc0[0]); r04.y = f2b(oacc0[1]); r04.z = f2b(oacc0[2]); r04.w = f2b(oacc0[3]);
    r14.x = f2b(oacc1[0]); r14.y = f2b(oacc1[1]); r14.z = f2b(oacc1[2]); r14.w = f2b(oacc1[3]);
    *(ushort4*)po = r04;
    *(ushort4*)(po + 16) = r14;
    if (qd == 0) {
        float2 ml; ml.x = rmax; ml.y = rsum;
        mlbuf[(quarter * 32 + bh) * 1024 + m] = ml;
    }
}

// ---------------------------------------------------------------------------
// Output GEMM with fused 4-way flash combine.
// Prologue: merge weights ew[pix][head][q] in LDS; A-frags assembled inline
// from the 4 partO quarters (coalesced ld8 x4 + fma + repack to bf16).
// grid (16 nt, 4 mt, 4 b), fp32 out.
// ---------------------------------------------------------------------------
__global__ __launch_bounds__(256) void gemm_oc(const ushort* CK partO, const float2* CK mlbuf,
                                               const ushort* CK W, const float* CK bias,
                                               float* CK Y) {
    __shared__ __align__(16) float ew[64][8][4];   // 8 KB
    const int b = blockIdx.z;
    const int t = threadIdx.x, w = t >> 6, l = t & 63;
    const int lm = l & 15, qd = l >> 4;
    const int m0 = blockIdx.y * 64 + (w & 1) * 32;
    const int n0 = blockIdx.x * 64 + (w >> 1) * 32;
    const int nblk = blockIdx.x * 64;

    for (int p = t; p < 512; p += 256) {
        const int pix = p >> 3, head = p & 7;
        const int mg = nblk + pix;
        const int bh = b * 8 + head;
        float2 ml[4];
        float M = -3e38f;
#pragma unroll
        for (int q2 = 0; q2 < 4; q2++) {
            ml[q2] = mlbuf[(q2 * 32 + bh) * 1024 + mg];
            M = fmaxf(M, ml[q2].x);
        }
        float e[4], den = 0.f;
#pragma unroll
        for (int q2 = 0; q2 < 4; q2++) { e[q2] = __expf(ml[q2].x - M); den += ml[q2].y * e[q2]; }
        const float inv = 1.f / den;
#pragma unroll
        for (int q2 = 0; q2 < 4; q2++) ew[pix][head][q2] = e[q2] * inv;
    }
    __syncthreads();

    const ushort* Bm = W + m0 * 256;
    f32x4 acc[2][2] = {};
#pragma unroll
    for (int k0 = 0; k0 < 8; k0++) {
        const int ko = k0 * 32 + qd * 8;
        short8 af[2];
#pragma unroll
        for (int half = 0; half < 2; half++) {
            const int pix_l = (w >> 1) * 32 + half * 16 + lm;
            const int mg = nblk + pix_l;
            const ushort* pbq = partO + ((b * 8 + k0) * 1024 + mg) * 32 + qd * 8;
            const float4 e4 = *(const float4*)&ew[pix_l][k0][0];
            float a8[8] = {};
#pragma unroll
            for (int q2 = 0; q2 < 4; q2++) {
                union { ushort u[8]; short8 s; } pv;
                pv.s = ld8(pbq + q2 * 1048576);
                const float eq = (q2 == 0) ? e4.x : (q2 == 1) ? e4.y : (q2 == 2) ? e4.z : e4.w;
#pragma unroll
                for (int j = 0; j < 8; j++) a8[j] += b2f(pv.u[j]) * eq;
            }
            union { ushort u[8]; short8 s; } out;
#pragma unroll
            for (int j = 0; j < 8; j++) out.u[j] = f2b(a8[j]);
            af[half] = out.s;
        }
        short8 b0 = ld8(Bm + lm * 256 + ko);
        short8 b1 = ld8(Bm + (16 + lm) * 256 + ko);
        acc[0][0] = __builtin_amdgcn_mfma_f32_16x16x32_bf16(af[0], b0, acc[0][0], 0, 0, 0);
        acc[0][1] = __builtin_amdgcn_mfma_f32_16x16x32_bf16(af[0], b1, acc[0][1], 0, 0, 0);
        acc[1][0] = __builtin_amdgcn_mfma_f32_16x16x32_bf16(af[1], b0, acc[1][0], 0, 0, 0);
        acc[1][1] = __builtin_amdgcn_mfma_f32_16x16x32_bf16(af[1], b1, acc[1][1], 0, 0, 0);
    }
#pragma unroll
    for (int in = 0; in < 2; in++)
#pragma unroll
        for (int im = 0; im < 2; im++) {
            const int mo = m0 + im * 16 + lm;
            const float bs = bias[mo];
            float4 r;
            r.x = acc[in][im][0] + bs; r.y = acc[in][im][1] + bs;
            r.z = acc[in][im][2] + bs; r.w = acc[in][im][3] + bs;
            *(float4*)(Y + b * 262144 + mo * HW + n0 + in * 16 + qd * 4) = r;
        }
}

// ---------------------------------------------------------------------------
extern "C" void kernel_launch(void* const* d_in, const int* in_sizes, int n_in,
                              void* d_out, int out_size, void* d_ws, size_t ws_size,
                              hipStream_t stream) {
    (void)in_sizes; (void)n_in; (void)out_size; (void)ws_size;
    const float* x   = (const float*)d_in[0];
    const float* wq  = (const float*)d_in[1];
    const float* bq  = (const float*)d_in[2];
    const float* wdw = (const float*)d_in[3];
    const float* bdw = (const float*)d_in[4];
    const float* lng = (const float*)d_in[5];
    const float* lnb = (const float*)d_in[6];
    const float* wpj = (const float*)d_in[7];
    const float* wk  = (const float*)d_in[8];
    const float* bk  = (const float*)d_in[9];
    const float* wv  = (const float*)d_in[10];
    const float* bv  = (const float*)d_in[11];
    const float* wo  = (const float*)d_in[12];
    const float* bo  = (const float*)d_in[13];
    const float* rpe = (const float*)d_in[14];
    float* outp = (float*)d_out;
    char* base = (char*)d_ws;
    const size_t MB = 1 << 20;

    ushort* q_b    = (ushort*)(base);                       // 2 MB  bf16 q
    ushort* kbt    = (ushort*)(base + 2 * MB);              // 2 MB
    ushort* vbs    = (ushort*)(base + 4 * MB);              // 2 MB
    // overlay @6MB..14MB: {off 4MB @6, xT 2MB @10, xsT 2MB @12} then partO 8MB
    float*  off_ws = (float*)(base + 6 * MB);
    ushort* xT     = (ushort*)(base + 10 * MB);
    ushort* xsT    = (ushort*)(base + 12 * MB);
    ushort* partO  = (ushort*)(base + 6 * MB);
    float2* mlbuf  = (float2*)(base + 14 * MB);             // 1 MB
    ushort* wqb    = (ushort*)(base + 15 * MB);
    ushort* wkb    = (ushort*)(base + 15 * MB + 131072);
    ushort* wvb    = (ushort*)(base + 15 * MB + 262144);
    ushort* wob    = (ushort*)(base + 15 * MB + 393216);
    float2* pos_sc = (float2*)(base + 15 * MB + 524288);    // 128 KB
    unsigned int* rpetab = (unsigned int*)(base + 15 * MB + 655360);  // 139 KB

    prep<<<392, 256, 0, stream>>>(wq, wk, wv, wo, wqb, wkb, wvb, wob, x, xT, rpe, rpetab);
    gemm_q<<<dim3(16, 4, 4), 256, 0, stream>>>(xT, wqb, bq, q_b);
    dwconv<<<1024, 256, 0, stream>>>(q_b, wdw, bdw, off_ws);
    lnps<<<256, 256, 0, stream>>>(off_ws, lng, lnb, wpj, x,
                                  outp + (1 << 20), outp + (1 << 20) + 32768, pos_sc, xsT);
    gemm_kv<<<dim3(16, 4, 4), 256, 0, stream>>>(xsT, wkb, bk, kbt, wvb, bv, vbs);
    attn_part<<<dim3(16, 32, 4), 256, 0, stream>>>(q_b, kbt, vbs, pos_sc, rpetab, partO, mlbuf);
    gemm_oc<<<dim3(16, 4, 4), 256, 0, stream>>>(partO, mlbuf, wob, bo, outp);
}